// Round 12
// baseline (6012.590 us; speedup 1.0000x reference)
//
#include <hip/hip_runtime.h>
#include <cstdint>

#define N_PTS 8192
#define M_PTS 4096
#define BS 4
#define CH 64
#define KNN 32
#define R2D (0.2 * 0.2)   // radius*radius in f64, matches Python
#define NCL 128           // 128 clusters of 64 sorted points

// ---- DPP helpers ----
template <int CTRL, int RM>
__device__ __forceinline__ float dppmax(float v) {
  int s = __builtin_amdgcn_update_dpp(__float_as_int(v), __float_as_int(v),
                                      CTRL, RM, 0xf, false);
  return fmaxf(v, __int_as_float(s));
}
__device__ __forceinline__ float readlane_f(float v, int l) {
  return __int_as_float(__builtin_amdgcn_readlane(__float_as_int(v), l));
}

__device__ __forceinline__ uint32_t part3(uint32_t x) {
  x &= 0x3FF;
  x = (x | (x << 16)) & 0x030000FF;
  x = (x | (x << 8))  & 0x0300F00F;
  x = (x | (x << 4))  & 0x030C30C3;
  x = (x | (x << 2))  & 0x09249249;
  return x;
}

// ---------------- FPS: one block per batch ----------------
// R8 skeleton (sorted-cluster prune + gated argmax + DPP + 1 barrier/iter) with:
//  - native-f32 md chain + screened rare f64 repair (exact md64 maintained)
//  - winner coords tracked in registers (no LDS gather on critical lane)
__global__ __launch_bounds__(1024, 4) void fps_kernel(const float* __restrict__ xyz,
                                                      float* __restrict__ child_xyz) {
  __shared__ float    sx[N_PTS], sy[N_PTS], sz[N_PTS];
  __shared__ uint32_t skey[N_PTS];
  __shared__ float    sclx[NCL], scly[NCL], sclz[NCL], sclr[NCL];
  __shared__ float    scomb[2][64];   // [pb][0:16)=proxy [16:32)=x [32:48)=y [48:64)=z
  __shared__ double   sbv[2][16];
  __shared__ int      sbi[2][16];

  const int b = blockIdx.x;
  const int t = threadIdx.x;
  const int lane = t & 63;
  const int wid  = t >> 6;
  const float* p = xyz + (size_t)b * N_PTS * 3;

  for (int e = t; e < N_PTS * 3; e += 1024) {
    float v = p[e];
    int i = e / 3, k = e - i * 3;
    if (k == 0) sx[i] = v; else if (k == 1) sy[i] = v; else sz[i] = v;
  }
  __syncthreads();

  // ---- Morton keys (18-bit) | original index (13-bit) ----
  for (int i = t; i < N_PTS; i += 1024) {
    uint32_t qx = (uint32_t)min(63, max(0, (int)((sx[i] + 8.0f) * 4.0f)));
    uint32_t qy = (uint32_t)min(63, max(0, (int)((sy[i] + 8.0f) * 4.0f)));
    uint32_t qz = (uint32_t)min(63, max(0, (int)((sz[i] + 8.0f) * 4.0f)));
    uint32_t mc = part3(qx) | (part3(qy) << 1) | (part3(qz) << 2);
    skey[i] = (mc << 13) | (uint32_t)i;
  }
  __syncthreads();

  // ---- bitonic sort (perf-only: affects pruning rate, not correctness) ----
  for (int k = 2; k <= N_PTS; k <<= 1) {
    for (int j = k >> 1; j > 0; j >>= 1) {
      for (int i = t; i < N_PTS; i += 1024) {
        int ixj = i ^ j;
        if (ixj > i) {
          uint32_t a = skey[i], c = skey[ixj];
          if (((i & k) == 0) ? (a > c) : (a < c)) { skey[i] = c; skey[ixj] = a; }
        }
      }
      __syncthreads();
    }
  }

  // ---- ownership (sorted order) + cluster bounds ----
  float pxf[8], pyf[8], pzf[8], md32n[8];
  int   oi[8];
  double md[8];
#pragma unroll
  for (int q = 0; q < 8; ++q) {
    const int c = wid * 8 + q;
    const int idx = (int)(skey[c * 64 + lane] & 0x1FFFu);
    oi[q] = idx;
    pxf[q] = sx[idx]; pyf[q] = sy[idx]; pzf[q] = sz[idx];
    md[q] = 1e10; md32n[q] = 1e10f;
    float cxs = pxf[q], cys = pyf[q], czs = pzf[q];
#pragma unroll
    for (int off = 32; off; off >>= 1) {
      cxs += __shfl_xor(cxs, off); cys += __shfl_xor(cys, off); czs += __shfl_xor(czs, off);
    }
    cxs *= (1.0f / 64.0f); cys *= (1.0f / 64.0f); czs *= (1.0f / 64.0f);
    float dx = pxf[q] - cxs, dy = pyf[q] - cys, dz = pzf[q] - czs;
    float r2 = dx * dx + dy * dy + dz * dz;
#pragma unroll
    for (int off = 32; off; off >>= 1) r2 = fmaxf(r2, __shfl_xor(r2, off));
    if (lane == 0) {
      sclx[c] = cxs; scly[c] = cys; sclz[c] = czs;
      sclr[c] = sqrtf(r2) * 1.0002f + 1e-5f;   // conservative upper radius
    }
  }
  __syncthreads();

  // lane q (q<8) keeps cluster (wid*8+q) bounds resident in VGPRs
  float ccx_r = 0.f, ccy_r = 0.f, ccz_r = 0.f, crad_r = 0.f;
  if (lane < 8) {
    const int c = wid * 8 + lane;
    ccx_r = sclx[c]; ccy_r = scly[c]; ccz_r = sclz[c]; crad_r = sclr[c];
  }

  // cached per-lane candidate state (coords in registers, not via LDS gather)
  double bv = -1.0; int bi = 0; float proxy = -1.0f;
  bool iwon = false;
  float bx_c = 0.f, by_c = 0.f, bz_c = 0.f;

  float gmaxf = 3.0e38f;                       // block-uniform prune bound
  float lx = sx[0], ly = sy[0], lz = sz[0];    // landmark 0 = point 0

  for (int it = 0; it < M_PTS; ++it) {
    if (t == 0) {
      float* o = child_xyz + ((size_t)b * M_PTS + it) * 3;
      o[0] = lx; o[1] = ly; o[2] = lz;
    }

    // ---- cluster skip test (lanes 0..7, f32, register-only) ----
    const float sg = sqrtf(gmaxf * 1.000002f + 1e-30f) * 1.000001f + 1e-4f;
    float dxc = ccx_r - lx, dyc = ccy_r - ly, dzc = ccz_r - lz;
    float d2c = dxc * dxc + dyc * dyc + dzc * dzc;
    float thr = crad_r + sg;
    bool need = !(d2c * 0.99999f >= thr * thr);
    const unsigned long long updm = __ballot((lane < 8) && need);

    // ---- native-f32 update + screen; exact f64 repair only when screened ----
    // screen: d2f <= md32n*(1+1e-4)+1e-12 provably catches every true f64
    // update (f32 rel errs <= ~4e-7; md32n >= md64*(1-eps) invariant).
    bool changed = false;
    unsigned sneed = 0;
    if (updm) {
#pragma unroll
      for (int q = 0; q < 8; ++q) {
        if ((updm >> q) & 1ull) {
          float dxf = pxf[q] - lx, dyf = pyf[q] - ly, dzf = pzf[q] - lz;
          float d2f = dxf * dxf + dyf * dyf + dzf * dzf;
          sneed |= (d2f <= md32n[q] * 1.0001f + 1e-12f) ? (1u << q) : 0u;
          md32n[q] = fminf(md32n[q], d2f);
        }
      }
      if (__any(sneed != 0)) {                 // single wave-uniform repair gate
        const double lxd = (double)lx, lyd = (double)ly, lzd = (double)lz;
#pragma unroll
        for (int q = 0; q < 8; ++q) {
          if ((updm >> q) & 1ull) {
            if (sneed & (1u << q)) {           // per-lane predication
              double dx = (double)pxf[q] - lxd;
              double dy = (double)pyf[q] - lyd;
              double dz = (double)pzf[q] - lzd;
              double d2 = dx * dx + dy * dy + dz * dz;
              bool c = d2 < md[q];
              md[q] = c ? d2 : md[q];
              changed |= c;
            }
          }
        }
      }
    }

    // ---- wave argmax (R8 gate): recompute only if some md64 changed ----
    if (__any(changed)) {
      bv = md[0];
#pragma unroll
      for (int q = 1; q < 8; ++q) bv = fmax(bv, md[q]);
      bi = 0x7fffffff;
#pragma unroll
      for (int q = 0; q < 8; ++q) {
        if (md[q] == bv && oi[q] < bi) {
          bi = oi[q]; bx_c = pxf[q]; by_c = pyf[q]; bz_c = pzf[q];
        }
      }
      proxy = (float)bv;

      // wave max via DPP (f32 proxy)
      float v = proxy;
      v = dppmax<0x111, 0xf>(v);   // row_shr:1
      v = dppmax<0x112, 0xf>(v);   // row_shr:2
      v = dppmax<0x114, 0xf>(v);   // row_shr:4
      v = dppmax<0x118, 0xf>(v);   // row_shr:8
      v = dppmax<0x142, 0xa>(v);   // row_bcast:15
      v = dppmax<0x143, 0xc>(v);   // row_bcast:31
      const float wmax = readlane_f(v, 63);

      const unsigned long long m = __ballot(proxy == wmax);
      bool iwon_now;
      if (__popcll(m) == 1) {                  // unique proxy winner (common)
        iwon_now = (lane == (int)(__ffsll(m) - 1));
      } else {                                 // rare: exact f64-lex butterfly
        double tv = bv; int ti = bi;
#pragma unroll
        for (int off = 32; off; off >>= 1) {
          double ov = __shfl_xor(tv, off);
          int    oib = __shfl_xor(ti, off);
          if (ov > tv || (ov == tv && oib < ti)) { tv = ov; ti = oib; }
        }
        iwon_now = (bv == tv) && (bi == ti);   // bi unique -> exactly one lane
      }
      iwon = iwon_now;
    }

    // ---- publish wave candidate (fresh or cached; registers only) ----
    const int pb = it & 1;
    if (iwon) {
      scomb[pb][wid]      = proxy;
      scomb[pb][16 + wid] = bx_c;
      scomb[pb][32 + wid] = by_c;
      scomb[pb][48 + wid] = bz_c;
      sbv[pb][wid] = bv; sbi[pb][wid] = bi;
    }
    __syncthreads();   // single barrier per iteration

    // ---- cross-wave: one LDS read/lane + 4-step DPP row reduce ----
    const float cval = scomb[pb][lane];
    float r = cval;
    r = dppmax<0x111, 0xf>(r);
    r = dppmax<0x112, 0xf>(r);
    r = dppmax<0x114, 0xf>(r);
    r = dppmax<0x118, 0xf>(r);
    const float gmax = readlane_f(r, 15);
    const unsigned long long gm = __ballot((lane < 16) && (cval == gmax));
    int w;
    if (__popcll(gm) == 1) {
      w = (int)(__ffsll(gm) - 1);
    } else {                                   // rare: exact f64 lex over tied waves
      double bestv = -1.0; int besti = 0x7fffffff; w = 0;
      for (int ww = 0; ww < 16; ++ww) if ((gm >> ww) & 1) {
        double vv = sbv[pb][ww]; int ii = sbi[pb][ww];
        if (vv > bestv || (vv == bestv && ii < besti)) { bestv = vv; besti = ii; w = ww; }
      }
    }
    const int ws = __builtin_amdgcn_readfirstlane(w);
    lx = readlane_f(cval, 16 + ws);
    ly = readlane_f(cval, 32 + ws);
    lz = readlane_f(cval, 48 + ws);
    gmaxf = gmax;                              // prune bound for next iteration
  }
}

// ---------------- feats (b,c,n) -> featsT (b,n,c) ----------------
__global__ __launch_bounds__(256) void transpose_kernel(const float* __restrict__ feats,
                                                        float* __restrict__ featsT) {
  __shared__ float tile[CH][65];
  const int b = blockIdx.y;
  const int i0 = blockIdx.x * 64;
  const int t = threadIdx.x;
  const float* src = feats + (size_t)b * CH * N_PTS;
#pragma unroll
  for (int r = 0; r < 16; ++r) {
    int e = t + r * 256;
    int c = e >> 6, ii = e & 63;
    tile[c][ii] = src[(size_t)c * N_PTS + i0 + ii];
  }
  __syncthreads();
  float* dst = featsT + ((size_t)b * N_PTS + i0) * CH;
#pragma unroll
  for (int r = 0; r < 16; ++r) {
    int e = t + r * 256;
    int ii = e >> 6, c = e & 63;
    dst[(size_t)ii * CH + c] = tile[c][ii];
  }
}

// ---------------- ball query (first-K ascending index) + feature max, fused ----------------
__global__ __launch_bounds__(1024) void ballgroup_kernel(const float* __restrict__ xyz,
                                                         const float* __restrict__ child_xyz,
                                                         const float* __restrict__ featsrc,
                                                         float* __restrict__ child_feats,
                                                         int useT) {
  __shared__ float sx[N_PTS], sy[N_PTS], sz[N_PTS];
  __shared__ int slist[16][KNN];
  const int b = blockIdx.y;
  const int t = threadIdx.x;
  const int lane = t & 63, wid = t >> 6;
  const float* p = xyz + (size_t)b * N_PTS * 3;
  for (int e = t; e < N_PTS * 3; e += 1024) {
    float v = p[e];
    int i = e / 3, k = e - i * 3;
    if (k == 0) sx[i] = v; else if (k == 1) sy[i] = v; else sz[i] = v;
  }
  __syncthreads();

  const int j = blockIdx.x * 16 + wid;           // one wave per ball
  const float* cc = child_xyz + ((size_t)b * M_PTS + j) * 3;
  const double cx = (double)cc[0], cy = (double)cc[1], cz = (double)cc[2];

  int taken = 0;
  for (int i0 = 0; i0 < N_PTS && taken < KNN; i0 += 64) {
    const int i = i0 + lane;
    double dx = cx - (double)sx[i], dy = cy - (double)sy[i], dz = cz - (double)sz[i];
    double d2 = dx * dx + dy * dy + dz * dz;
    const bool hit = d2 <= R2D;
    const unsigned long long msk = __ballot(hit);
    if (msk) {
      int slot = taken + __popcll(msk & ((1ull << lane) - 1ull));
      if (hit && slot < KNN) slist[wid][slot] = i;
      taken += (int)__popcll(msk);
    }
  }
  int cnt = taken < KNN ? taken : KNN;
  if (cnt == 0) { if (lane == 0) slist[wid][0] = 0; cnt = 1; }

  float acc = -INFINITY;
  for (int q = 0; q < cnt; ++q) {
    const int idx = slist[wid][q];
    float v = useT ? featsrc[((size_t)b * N_PTS + idx) * CH + lane]
                   : featsrc[((size_t)b * CH + lane) * N_PTS + idx];
    acc = fmaxf(acc, v);
  }
  child_feats[((size_t)b * CH + lane) * M_PTS + j] = acc;
}

extern "C" void kernel_launch(void* const* d_in, const int* in_sizes, int n_in,
                              void* d_out, int out_size, void* d_ws, size_t ws_size,
                              hipStream_t stream) {
  const float* xyz   = (const float*)d_in[0];
  const float* feats = (const float*)d_in[1];
  float* out = (float*)d_out;
  float* child_xyz   = out;
  float* child_feats = out + (size_t)BS * M_PTS * 3;
  float* featsT = (float*)d_ws;
  const int useT = ws_size >= (size_t)BS * N_PTS * CH * sizeof(float);

  fps_kernel<<<BS, 1024, 0, stream>>>(xyz, child_xyz);
  if (useT) transpose_kernel<<<dim3(N_PTS / 64, BS), 256, 0, stream>>>(feats, featsT);
  ballgroup_kernel<<<dim3(M_PTS / 16, BS), 1024, 0, stream>>>(
      xyz, child_xyz, useT ? featsT : feats, child_feats, useT);
}

// Round 13
// 4296.788 us; speedup vs baseline: 1.3993x; 1.3993x over previous
//
#include <hip/hip_runtime.h>
#include <cstdint>

#define N_PTS 8192
#define M_PTS 4096
#define BS 4
#define CH 64
#define KNN 32
#define R2D (0.2 * 0.2)   // radius*radius in f64, matches Python
#define NCL 128           // 128 clusters of 64 sorted points

// ---- DPP helpers ----
template <int CTRL, int RM>
__device__ __forceinline__ float dppmax(float v) {
  int s = __builtin_amdgcn_update_dpp(__float_as_int(v), __float_as_int(v),
                                      CTRL, RM, 0xf, false);
  return fmaxf(v, __int_as_float(s));
}
__device__ __forceinline__ float readlane_f(float v, int l) {
  return __int_as_float(__builtin_amdgcn_readlane(__float_as_int(v), l));
}

__device__ __forceinline__ uint32_t part3(uint32_t x) {
  x &= 0x3FF;
  x = (x | (x << 16)) & 0x030000FF;
  x = (x | (x << 8))  & 0x0300F00F;
  x = (x | (x << 4))  & 0x030C30C3;
  x = (x | (x << 2))  & 0x09249249;
  return x;
}

// ---------------- FPS: one block per batch ----------------
// R8 skeleton, with INTERLEAVED cluster->wave assignment: cluster c = q*16+wid.
// Hot (non-prunable) clusters near the landmark are spatially adjacent after
// the Morton sort; interleaving spreads them across all 16 waves / 4 SIMDs so
// no single SIMD serializes the hot f64 work while others wait at the barrier.
__global__ __launch_bounds__(1024, 4) void fps_kernel(const float* __restrict__ xyz,
                                                      float* __restrict__ child_xyz) {
  __shared__ float    sx[N_PTS], sy[N_PTS], sz[N_PTS];
  __shared__ uint32_t skey[N_PTS];
  __shared__ float    sclx[NCL], scly[NCL], sclz[NCL], sclr[NCL];
  __shared__ float    scomb[2][64];   // [pb][0:16)=proxy [16:32)=x [32:48)=y [48:64)=z
  __shared__ double   sbv[2][16];
  __shared__ int      sbi[2][16];

  const int b = blockIdx.x;
  const int t = threadIdx.x;
  const int lane = t & 63;
  const int wid  = t >> 6;
  const float* p = xyz + (size_t)b * N_PTS * 3;

  for (int e = t; e < N_PTS * 3; e += 1024) {
    float v = p[e];
    int i = e / 3, k = e - i * 3;
    if (k == 0) sx[i] = v; else if (k == 1) sy[i] = v; else sz[i] = v;
  }
  __syncthreads();

  // ---- Morton keys (18-bit) | original index (13-bit) ----
  for (int i = t; i < N_PTS; i += 1024) {
    uint32_t qx = (uint32_t)min(63, max(0, (int)((sx[i] + 8.0f) * 4.0f)));
    uint32_t qy = (uint32_t)min(63, max(0, (int)((sy[i] + 8.0f) * 4.0f)));
    uint32_t qz = (uint32_t)min(63, max(0, (int)((sz[i] + 8.0f) * 4.0f)));
    uint32_t mc = part3(qx) | (part3(qy) << 1) | (part3(qz) << 2);
    skey[i] = (mc << 13) | (uint32_t)i;
  }
  __syncthreads();

  // ---- bitonic sort (perf-only: affects pruning rate, not correctness) ----
  for (int k = 2; k <= N_PTS; k <<= 1) {
    for (int j = k >> 1; j > 0; j >>= 1) {
      for (int i = t; i < N_PTS; i += 1024) {
        int ixj = i ^ j;
        if (ixj > i) {
          uint32_t a = skey[i], c = skey[ixj];
          if (((i & k) == 0) ? (a > c) : (a < c)) { skey[i] = c; skey[ixj] = a; }
        }
      }
      __syncthreads();
    }
  }

  // ---- ownership (sorted order, INTERLEAVED c = q*16 + wid) + cluster bounds ----
  float pxf[8], pyf[8], pzf[8];
  int   oi[8];
  double md[8];
#pragma unroll
  for (int q = 0; q < 8; ++q) {
    const int c = q * 16 + wid;                // interleaved cluster id
    const int idx = (int)(skey[c * 64 + lane] & 0x1FFFu);
    oi[q] = idx;
    pxf[q] = sx[idx]; pyf[q] = sy[idx]; pzf[q] = sz[idx];
    md[q] = 1e10;
    float cxs = pxf[q], cys = pyf[q], czs = pzf[q];
#pragma unroll
    for (int off = 32; off; off >>= 1) {
      cxs += __shfl_xor(cxs, off); cys += __shfl_xor(cys, off); czs += __shfl_xor(czs, off);
    }
    cxs *= (1.0f / 64.0f); cys *= (1.0f / 64.0f); czs *= (1.0f / 64.0f);
    float dx = pxf[q] - cxs, dy = pyf[q] - cys, dz = pzf[q] - czs;
    float r2 = dx * dx + dy * dy + dz * dz;
#pragma unroll
    for (int off = 32; off; off >>= 1) r2 = fmaxf(r2, __shfl_xor(r2, off));
    if (lane == 0) {
      sclx[c] = cxs; scly[c] = cys; sclz[c] = czs;
      sclr[c] = sqrtf(r2) * 1.0002f + 1e-5f;   // conservative upper radius
    }
  }
  __syncthreads();

  // lane q (q<8) keeps cluster (q*16+wid) bounds resident in VGPRs
  float ccx_r = 0.f, ccy_r = 0.f, ccz_r = 0.f, crad_r = 0.f;
  if (lane < 8) {
    const int c = lane * 16 + wid;             // matches md[q]/pxf[q] mapping
    ccx_r = sclx[c]; ccy_r = scly[c]; ccz_r = sclz[c]; crad_r = sclr[c];
  }

  // cached per-lane candidate state
  double bv = -1.0; int bi = 0; float proxy = -1.0f;
  bool iwon = false;
  float cx_c = 0.f, cy_c = 0.f, cz_c = 0.f;

  float gmaxf = 3.0e38f;                       // block-uniform prune bound
  float lx = sx[0], ly = sy[0], lz = sz[0];    // landmark 0 = point 0

  for (int it = 0; it < M_PTS; ++it) {
    if (t == 0) {
      float* o = child_xyz + ((size_t)b * M_PTS + it) * 3;
      o[0] = lx; o[1] = ly; o[2] = lz;
    }
    const double lxd = (double)lx, lyd = (double)ly, lzd = (double)lz;

    // ---- cluster skip test (lanes 0..7, f32, register-only) ----
    // skip cluster iff d(c,l) - rad >= sqrt(gmax)  (fat conservative margins)
    const float sg = sqrtf(gmaxf * 1.000002f + 1e-30f) * 1.000001f + 1e-4f;
    float dxc = ccx_r - lx, dyc = ccy_r - ly, dzc = ccz_r - lz;
    float d2c = dxc * dxc + dyc * dyc + dzc * dzc;
    float thr = crad_r + sg;
    bool need = !(d2c * 0.99999f >= thr * thr);
    const unsigned long long updm = __ballot((lane < 8) && need);

    // ---- exact f64 min-dist update, only for non-pruned clusters ----
    bool changed = false;
    if (updm) {
#pragma unroll
      for (int q = 0; q < 8; ++q) {
        if ((updm >> q) & 1ull) {
          double dx = (double)pxf[q] - lxd, dy = (double)pyf[q] - lyd, dz = (double)pzf[q] - lzd;
          double d2 = dx * dx + dy * dy + dz * dz;
          bool c = d2 < md[q];
          md[q] = c ? d2 : md[q];
          changed |= c;
        }
      }
    }

    // ---- wave argmax: recompute only if some md in wave changed ----
    if (__any(changed)) {
      bv = md[0];
#pragma unroll
      for (int q = 1; q < 8; ++q) bv = fmax(bv, md[q]);
      bi = 0x7fffffff;
#pragma unroll
      for (int q = 0; q < 8; ++q) if (md[q] == bv && oi[q] < bi) bi = oi[q];
      proxy = (float)bv;

      // wave max via DPP (f32 proxy)
      float v = proxy;
      v = dppmax<0x111, 0xf>(v);   // row_shr:1
      v = dppmax<0x112, 0xf>(v);   // row_shr:2
      v = dppmax<0x114, 0xf>(v);   // row_shr:4
      v = dppmax<0x118, 0xf>(v);   // row_shr:8
      v = dppmax<0x142, 0xa>(v);   // row_bcast:15
      v = dppmax<0x143, 0xc>(v);   // row_bcast:31
      const float wmax = readlane_f(v, 63);

      const unsigned long long m = __ballot(proxy == wmax);
      bool iwon_now;
      if (__popcll(m) == 1) {                  // unique proxy winner (common)
        iwon_now = (lane == (int)(__ffsll(m) - 1));
      } else {                                 // rare: exact f64-lex butterfly
        double tv = bv; int ti = bi;
#pragma unroll
        for (int off = 32; off; off >>= 1) {
          double ov = __shfl_xor(tv, off);
          int    oib = __shfl_xor(ti, off);
          if (ov > tv || (ov == tv && oib < ti)) { tv = ov; ti = oib; }
        }
        iwon_now = (bv == tv) && (bi == ti);   // bi unique -> exactly one lane
      }
      iwon = iwon_now;
      if (iwon) { cx_c = sx[bi]; cy_c = sy[bi]; cz_c = sz[bi]; }
    }

    // ---- publish wave candidate (fresh or cached; parity needs republish) ----
    const int pb = it & 1;
    if (iwon) {
      scomb[pb][wid]      = proxy;
      scomb[pb][16 + wid] = cx_c;
      scomb[pb][32 + wid] = cy_c;
      scomb[pb][48 + wid] = cz_c;
      sbv[pb][wid] = bv; sbi[pb][wid] = bi;
    }
    __syncthreads();   // single barrier per iteration

    // ---- cross-wave: one LDS read/lane + 4-step DPP row reduce ----
    const float cval = scomb[pb][lane];
    float r = cval;
    r = dppmax<0x111, 0xf>(r);
    r = dppmax<0x112, 0xf>(r);
    r = dppmax<0x114, 0xf>(r);
    r = dppmax<0x118, 0xf>(r);
    const float gmax = readlane_f(r, 15);
    const unsigned long long gm = __ballot((lane < 16) && (cval == gmax));
    int w;
    if (__popcll(gm) == 1) {
      w = (int)(__ffsll(gm) - 1);
    } else {                                   // rare: exact f64 lex over tied waves
      double bestv = -1.0; int besti = 0x7fffffff; w = 0;
      for (int ww = 0; ww < 16; ++ww) if ((gm >> ww) & 1) {
        double vv = sbv[pb][ww]; int ii = sbi[pb][ww];
        if (vv > bestv || (vv == bestv && ii < besti)) { bestv = vv; besti = ii; w = ww; }
      }
    }
    const int ws = __builtin_amdgcn_readfirstlane(w);
    lx = readlane_f(cval, 16 + ws);
    ly = readlane_f(cval, 32 + ws);
    lz = readlane_f(cval, 48 + ws);
    gmaxf = gmax;                              // prune bound for next iteration
  }
}

// ---------------- feats (b,c,n) -> featsT (b,n,c) ----------------
__global__ __launch_bounds__(256) void transpose_kernel(const float* __restrict__ feats,
                                                        float* __restrict__ featsT) {
  __shared__ float tile[CH][65];
  const int b = blockIdx.y;
  const int i0 = blockIdx.x * 64;
  const int t = threadIdx.x;
  const float* src = feats + (size_t)b * CH * N_PTS;
#pragma unroll
  for (int r = 0; r < 16; ++r) {
    int e = t + r * 256;
    int c = e >> 6, ii = e & 63;
    tile[c][ii] = src[(size_t)c * N_PTS + i0 + ii];
  }
  __syncthreads();
  float* dst = featsT + ((size_t)b * N_PTS + i0) * CH;
#pragma unroll
  for (int r = 0; r < 16; ++r) {
    int e = t + r * 256;
    int ii = e >> 6, c = e & 63;
    dst[(size_t)ii * CH + c] = tile[c][ii];
  }
}

// ---------------- ball query (first-K ascending index) + feature max, fused ----------------
__global__ __launch_bounds__(1024) void ballgroup_kernel(const float* __restrict__ xyz,
                                                         const float* __restrict__ child_xyz,
                                                         const float* __restrict__ featsrc,
                                                         float* __restrict__ child_feats,
                                                         int useT) {
  __shared__ float sx[N_PTS], sy[N_PTS], sz[N_PTS];
  __shared__ int slist[16][KNN];
  const int b = blockIdx.y;
  const int t = threadIdx.x;
  const int lane = t & 63, wid = t >> 6;
  const float* p = xyz + (size_t)b * N_PTS * 3;
  for (int e = t; e < N_PTS * 3; e += 1024) {
    float v = p[e];
    int i = e / 3, k = e - i * 3;
    if (k == 0) sx[i] = v; else if (k == 1) sy[i] = v; else sz[i] = v;
  }
  __syncthreads();

  const int j = blockIdx.x * 16 + wid;           // one wave per ball
  const float* cc = child_xyz + ((size_t)b * M_PTS + j) * 3;
  const double cx = (double)cc[0], cy = (double)cc[1], cz = (double)cc[2];

  int taken = 0;
  for (int i0 = 0; i0 < N_PTS && taken < KNN; i0 += 64) {
    const int i = i0 + lane;
    double dx = cx - (double)sx[i], dy = cy - (double)sy[i], dz = cz - (double)sz[i];
    double d2 = dx * dx + dy * dy + dz * dz;
    const bool hit = d2 <= R2D;
    const unsigned long long msk = __ballot(hit);
    if (msk) {
      int slot = taken + __popcll(msk & ((1ull << lane) - 1ull));
      if (hit && slot < KNN) slist[wid][slot] = i;
      taken += (int)__popcll(msk);
    }
  }
  int cnt = taken < KNN ? taken : KNN;
  if (cnt == 0) { if (lane == 0) slist[wid][0] = 0; cnt = 1; }

  float acc = -INFINITY;
  for (int q = 0; q < cnt; ++q) {
    const int idx = slist[wid][q];
    float v = useT ? featsrc[((size_t)b * N_PTS + idx) * CH + lane]
                   : featsrc[((size_t)b * CH + lane) * N_PTS + idx];
    acc = fmaxf(acc, v);
  }
  child_feats[((size_t)b * CH + lane) * M_PTS + j] = acc;
}

extern "C" void kernel_launch(void* const* d_in, const int* in_sizes, int n_in,
                              void* d_out, int out_size, void* d_ws, size_t ws_size,
                              hipStream_t stream) {
  const float* xyz   = (const float*)d_in[0];
  const float* feats = (const float*)d_in[1];
  float* out = (float*)d_out;
  float* child_xyz   = out;
  float* child_feats = out + (size_t)BS * M_PTS * 3;
  float* featsT = (float*)d_ws;
  const int useT = ws_size >= (size_t)BS * N_PTS * CH * sizeof(float);

  fps_kernel<<<BS, 1024, 0, stream>>>(xyz, child_xyz);
  if (useT) transpose_kernel<<<dim3(N_PTS / 64, BS), 256, 0, stream>>>(feats, featsT);
  ballgroup_kernel<<<dim3(M_PTS / 16, BS), 1024, 0, stream>>>(
      xyz, child_xyz, useT ? featsT : feats, child_feats, useT);
}